// Round 4
// baseline (6441.748 us; speedup 1.0000x reference)
//
#include <hip/hip_runtime.h>
#include <hip/hip_bf16.h>

#define T_STEPS 256
#define BATCH   64
#define DIM_I   256
#define DIM_H   256
#define NBR     8
#define K_DIM   512
#define F_DIM   1024

typedef __attribute__((ext_vector_type(8))) short short8;
typedef __attribute__((ext_vector_type(4))) float floatx4;

__device__ __forceinline__ float sigmoid_fast(float x) {
    return 1.0f / (1.0f + __expf(-x));
}
__device__ __forceinline__ float tanh_fast(float x) {
    return 1.0f - 2.0f / (__expf(2.0f * x) + 1.0f);
}
// fp32 -> bf16 bits, round-to-nearest-even (finite inputs only)
__device__ __forceinline__ short f2bf(float f) {
    unsigned u = __float_as_uint(f);
    u += 0x7FFFu + ((u >> 16) & 1u);
    return (short)(u >> 16);
}

// ---------------------------------------------------------------------------
// ws layout (bytes):
//   [0, 4K)        counters: 16 groups, padded 256 B apart
//   [4K, 4K+512K)  hfrag: [ph][n][pm][hc] 1KB A-frags of h (pm = p*2+mw)
//   [1M, 9M)       Wtg:   [n][cg][kt][cf][lane][8] bf16 (B-fragment order)
//   [9M, 17M)      xfrag: [t][pm][kt][lane][8] bf16 (A-fragment order)
// ---------------------------------------------------------------------------
#define WS_HFRAG  (4 * 1024)
#define WS_WTG    (1024 * 1024)
#define WS_XFRAG  (9 * 1024 * 1024)

// Wtg element: frag G = (((n*16+cg)*16 + kt)*4 + cf)*64 + lane holds
//   W[n][kt*32 + (lane>>4)*8 + jj][cf*256 + cg*16 + (lane&15)], jj=0..7
__global__ void __launch_bounds__(256)
prep_w(const float* __restrict__ W, short* __restrict__ Wtg) {
    int G    = blockIdx.x * 256 + threadIdx.x;   // 0..524287
    int lane = G & 63;
    int cf   = (G >> 6) & 3;
    int kt   = (G >> 8) & 15;
    int cg   = (G >> 12) & 15;
    int n    = G >> 16;
    int k0   = kt * 32 + (lane >> 4) * 8;
    int f    = cf * 256 + cg * 16 + (lane & 15);
    const float* src = W + ((size_t)(n * K_DIM + k0)) * F_DIM + f;
    short8 v;
#pragma unroll
    for (int jj = 0; jj < 8; ++jj) v[jj] = f2bf(src[(size_t)jj * F_DIM]);
    *reinterpret_cast<short8*>(Wtg + (size_t)G * 8) = v;
}

// xfrag: frag G = ((t*4 + pm)*8 + kt)*64 + lane holds
//   x[t][pm*16 + (lane&15)][kt*32 + (lane>>4)*8 + jj]
__global__ void __launch_bounds__(256)
prep_x(const float* __restrict__ x, short* __restrict__ xfrag) {
    int G    = blockIdx.x * 256 + threadIdx.x;   // 0..524287
    int lane = G & 63;
    int kt   = (G >> 6) & 7;
    int pm   = (G >> 9) & 3;
    int t    = G >> 11;
    int row  = pm * 16 + (lane & 15);
    int k0   = kt * 32 + (lane >> 4) * 8;
    const float4* src = reinterpret_cast<const float4*>(
        x + ((size_t)t * BATCH + row) * DIM_I + k0);
    float4 a0 = src[0];
    float4 a1 = src[1];
    short8 v;
    v[0] = f2bf(a0.x); v[1] = f2bf(a0.y); v[2] = f2bf(a0.z); v[3] = f2bf(a0.w);
    v[4] = f2bf(a1.x); v[5] = f2bf(a1.y); v[6] = f2bf(a1.z); v[7] = f2bf(a1.w);
    *reinterpret_cast<short8*>(xfrag + (size_t)G * 8) = v;
}

// Grid: 256 blocks x 128 threads (2 waves).
// bid = cg*16 + gid;  gid = n*2 + p  -> sync group gid, all on XCD gid%8.
// Block owns H-cols [cg*16, cg*16+16) x 4 gates, rows [p*32, p*32+32)
// (wave mw = 16-row M-tile). W slice (64 KB) LDS-resident; A-frags in regs.
__global__ void __launch_bounds__(128, 1)
durlm_kernel(const int* __restrict__ dur,
             const float* __restrict__ bias_i,
             const float* __restrict__ bias_h,
             float* __restrict__ out,
             const short* __restrict__ Wtg,
             const short* __restrict__ xfrag,
             short* __restrict__ hfrag,
             unsigned int* __restrict__ counters)
{
    __shared__ short Wlds[16 * 4 * 64 * 8];   // 64 KB
    __shared__ short tbuf[2][16 * 24];        // per-wave transpose, stride 24

    const int tid  = threadIdx.x;
    const int lane = tid & 63;
    const int mw   = tid >> 6;           // wave -> M-tile
    const int bid  = blockIdx.x;
    const int cg   = bid >> 4;           // H-col chunk 0..15
    const int gid  = bid & 15;           // sync group -> XCD gid%8
    const int n    = gid >> 1;           // branch
    const int p    = gid & 1;            // batch half
    const int q    = lane >> 4;
    const int l15  = lane & 15;
    const int pm   = p * 2 + mw;
    const int rowbase = p * 32 + mw * 16;

    // ---- stage W slice (64 KB) from pre-swizzled global, identical layout ----
    {
        const float4* src = reinterpret_cast<const float4*>(
            Wtg + (size_t)(n * 16 + cg) * 4096 * 8);
        float4* dst = reinterpret_cast<float4*>(Wlds);
#pragma unroll
        for (int i = 0; i < 32; ++i) dst[tid + i * 128] = src[tid + i * 128];
    }

    float bias[4];
#pragma unroll
    for (int cf = 0; cf < 4; ++cf) {
        int f = cf * 256 + cg * 16 + l15;
        bias[cf] = bias_i[n * F_DIM + f] + bias_h[n * F_DIM + f];
    }
    __syncthreads();

    const short* xf = xfrag + (size_t)pm * 8 * 512 + lane * 8;
    short8 ax[8];
#pragma unroll
    for (int kt = 0; kt < 8; ++kt)
        ax[kt] = *reinterpret_cast<const short8*>(xf + kt * 512);   // t=0

    float c_state[4] = {0.f, 0.f, 0.f, 0.f};

    for (int t = 0; t < T_STEPS; ++t) {
        const int ph = t & 1;

        // h A-frags (written in fragment order by the 16 group blocks)
        short8 ah[8];
        const short* hfb =
            hfrag + ((((size_t)ph * 8 + n) * 4 + pm) * 8) * 512 + lane * 8;
#pragma unroll
        for (int hc = 0; hc < 8; ++hc)
            ah[hc] = *reinterpret_cast<const short8*>(hfb + hc * 512);

        int dv[4];
#pragma unroll
        for (int r = 0; r < 4; ++r)
            dv[r] = dur[t * BATCH + rowbase + q * 4 + r];

        floatx4 acc[4];
#pragma unroll
        for (int cf = 0; cf < 4; ++cf) acc[cf] = (floatx4){0.f, 0.f, 0.f, 0.f};

#pragma unroll
        for (int kt = 0; kt < 8; ++kt)
#pragma unroll
            for (int cf = 0; cf < 4; ++cf) {
                short8 b = *reinterpret_cast<const short8*>(
                    &Wlds[((kt * 4 + cf) * 64 + lane) * 8]);
                acc[cf] = __builtin_amdgcn_mfma_f32_16x16x32_bf16(
                    ax[kt], b, acc[cf], 0, 0, 0);
            }

        // prefetch next step's x-frags (hides under MFMA + barrier wait)
        if (t + 1 < T_STEPS) {
            const short* xf2 = xf + (size_t)(t + 1) * 4 * 8 * 512;
#pragma unroll
            for (int kt = 0; kt < 8; ++kt)
                ax[kt] = *reinterpret_cast<const short8*>(xf2 + kt * 512);
        }

#pragma unroll
        for (int kt = 0; kt < 8; ++kt)
#pragma unroll
            for (int cf = 0; cf < 4; ++cf) {
                short8 b = *reinterpret_cast<const short8*>(
                    &Wlds[(((8 + kt) * 4 + cf) * 64 + lane) * 8]);
                acc[cf] = __builtin_amdgcn_mfma_f32_16x16x32_bf16(
                    ah[kt], b, acc[cf], 0, 0, 0);
            }

        // ---- lane-local LSTM epilogue (C/D: col=l15, row=q*4+r) ----
#pragma unroll
        for (int r = 0; r < 4; ++r) {
            int row = rowbase + q * 4 + r;
            bool freeze = n > (dv[r] >> 3);
            float zi = acc[0][r] + bias[0];
            float zf = acc[1][r] + bias[1];
            float zo = acc[2][r] + bias[2];
            float zg = acc[3][r] + bias[3];
            float ig = sigmoid_fast(zi);
            float fg = sigmoid_fast(zf);
            float og = sigmoid_fast(zo);
            float gg = tanh_fast(zg);
            float cn = freeze ? c_state[r] : fg * c_state[r] + ig * gg;
            c_state[r] = cn;
            float hv = og * tanh_fast(cn);
            __builtin_nontemporal_store(
                hv, &out[(((size_t)t * NBR + n) * BATCH + row) * DIM_H
                         + cg * 16 + l15]);
            tbuf[mw][(q * 4 + r) * 24 + l15] = f2bf(hv);   // C-layout -> LDS
        }

        if (t + 1 < T_STEPS) {
            // transpose-read 16 B in A-frag order; half-frag -> global hfrag
            // (this block produces k-local cols [(cg&1)*16, +16) of frag cg>>1)
            if ((q >> 1) == (cg & 1)) {
                short8 hv8 = *reinterpret_cast<const short8*>(
                    &tbuf[mw][l15 * 24 + (q & 1) * 8]);
                short* dstp = hfrag +
                    (((((size_t)((t + 1) & 1)) * 8 + n) * 4 + pm) * 8 + (cg >> 1))
                        * 512 + lane * 8;
                *reinterpret_cast<short8*>(dstp) = hv8;
            }

            // ---- same-XCD barrier over the 16 blocks of group gid ----
            __threadfence();   // drain + make h stores agent-visible
            __syncthreads();
            if (tid == 0) {
                __hip_atomic_fetch_add(&counters[gid * 64], 1u, __ATOMIC_RELEASE,
                                       __HIP_MEMORY_SCOPE_AGENT);
                unsigned target = (unsigned)(t + 1) * 16u;
                while (__hip_atomic_load(&counters[gid * 64], __ATOMIC_ACQUIRE,
                                         __HIP_MEMORY_SCOPE_AGENT) < target) {}
            }
            __syncthreads();
            __threadfence();   // invalidate L1 before next h-frag reads
        }
    }
}

extern "C" void kernel_launch(void* const* d_in, const int* in_sizes, int n_in,
                              void* d_out, int out_size, void* d_ws, size_t ws_size,
                              hipStream_t stream) {
    const float* x      = (const float*)d_in[0];
    const int*   durp   = (const int*)d_in[1];
    const float* weight = (const float*)d_in[2];
    const float* bias_i = (const float*)d_in[3];
    const float* bias_h = (const float*)d_in[4];
    float* out = (float*)d_out;

    unsigned int* counters = (unsigned int*)d_ws;
    short*        hfrag    = (short*)((char*)d_ws + WS_HFRAG);
    short*        Wtg      = (short*)((char*)d_ws + WS_WTG);
    short*        xfrag    = (short*)((char*)d_ws + WS_XFRAG);

    // zero counters + both hfrag phases (h_0 = 0)
    hipMemsetAsync(d_ws, 0, WS_HFRAG + 512 * 1024, stream);
    prep_w<<<2048, 256, 0, stream>>>(weight, Wtg);
    prep_x<<<2048, 256, 0, stream>>>(x, xfrag);
    durlm_kernel<<<256, 128, 0, stream>>>(durp, bias_i, bias_h, out,
                                          Wtg, xfrag, hfrag, counters);
}